// Round 2
// baseline (349.376 us; speedup 1.0000x reference)
//
#include <hip/hip_runtime.h>
#include <hip/hip_bf16.h>

// GAT layer: B=8, N=2048, Fin=256, Fout=128
// Wh = h@W ; s1 = Wh@a1 ; s2 = Wh@a2
// att[b,i,j] = softmax_over_i( lrelu(s1_i + s2_j) )   (normalizer per column j)
// out = elu( att @ Wh )
//
// Input dtype is detected ON-DEVICE (f32 vs bf16) and kernels are dual-
// instantiated with a uniform flag guard — resolves the harness dtype
// ambiguity in one round.

#define ALPHA 0.2f
constexpr int Bb  = 8;
constexpr int Nn  = 2048;
constexpr int FIN = 256;
constexpr int FOUT= 128;

__device__ __forceinline__ float lrelu(float x){ return x >= 0.f ? x : ALPHA * x; }
__device__ __forceinline__ float ldf(const float* p){ return *p; }
__device__ __forceinline__ float ldf(const __hip_bfloat16* p){ return __bfloat162float(*p); }

// ---- dtype probe: flag=1 if inputs are f32, flag=0 if bf16 ----
// Reads even-index 16-bit words of h. If the buffer is f32, those are random
// mantissa halves -> decoded as bf16 some are astronomically large (P~1).
// If the buffer is bf16 of N(0,1) data, all values are < 10.
__global__ __launch_bounds__(64) void k_flag(const unsigned short* __restrict__ h16,
                                             int* __restrict__ flag){
    const int t = threadIdx.x;
    unsigned int bits = ((unsigned int)h16[t * 2]) << 16;
    float v = __uint_as_float(bits);
    bool big = !(fabsf(v) < 1e6f);           // catches huge / inf / NaN
    unsigned long long m = __ballot(big);
    if (t == 0) flag[0] = (m != 0ULL) ? 1 : 0;
}

// ---- K1: Wh[row,:] (f32 in ws), s1[row], s2[row].  grid=B*N, 128 thr ----
template<typename T, int WANT>
__global__ __launch_bounds__(128) void k_wh(const T* __restrict__ h,
                                            const T* __restrict__ W,
                                            const T* __restrict__ a,
                                            const int* __restrict__ flag,
                                            float* __restrict__ Wh,
                                            float* __restrict__ s1,
                                            float* __restrict__ s2){
    if (flag[0] != WANT) return;
    const int row = blockIdx.x;
    const int t   = threadIdx.x;
    __shared__ float hs[FIN];
    hs[t]       = ldf(&h[(size_t)row*FIN + t]);
    hs[t + 128] = ldf(&h[(size_t)row*FIN + t + 128]);
    __syncthreads();
    float acc = 0.f;
    #pragma unroll 8
    for (int i = 0; i < FIN; ++i)
        acc += hs[i] * ldf(&W[i*FOUT + t]);
    Wh[(size_t)row*FOUT + t] = acc;

    float p1 = acc * ldf(&a[t]);
    float p2 = acc * ldf(&a[FOUT + t]);
    #pragma unroll
    for (int off = 32; off > 0; off >>= 1){
        p1 += __shfl_down(p1, off);
        p2 += __shfl_down(p2, off);
    }
    __shared__ float red[4];
    const int lane = t & 63, wid = t >> 6;
    if (lane == 0){ red[wid] = p1; red[2 + wid] = p2; }
    __syncthreads();
    if (t == 0){ s1[row] = red[0] + red[1]; s2[row] = red[2] + red[3]; }
}

// ---- K2: s1max[b] = max_i s1[b,i].  grid=B, 256 thr ----
__global__ __launch_bounds__(256) void k_max(const float* __restrict__ s1,
                                             float* __restrict__ s1max){
    const int b = blockIdx.x, t = threadIdx.x;
    float m = -1e30f;
    for (int i = t; i < Nn; i += 256) m = fmaxf(m, s1[b*Nn + i]);
    #pragma unroll
    for (int off = 32; off > 0; off >>= 1) m = fmaxf(m, __shfl_down(m, off));
    __shared__ float red[4];
    if ((t & 63) == 0) red[t >> 6] = m;
    __syncthreads();
    if (t == 0) s1max[b] = fmaxf(fmaxf(red[0], red[1]), fmaxf(red[2], red[3]));
}

// ---- K3: invZ[b,j] = 1/sum_i exp(lrelu(s1_i+s2_j) - m_j) ----
__global__ __launch_bounds__(256) void k_z(const float* __restrict__ s1,
                                           const float* __restrict__ s2,
                                           const float* __restrict__ s1max,
                                           float* __restrict__ invZ){
    const int b  = blockIdx.x >> 5;
    const int jt = blockIdx.x & 31;
    const int t  = threadIdx.x;
    const int jj = t & 63, part = t >> 6;
    const int j  = jt * 64 + jj;
    __shared__ float s1s[Nn];
    for (int i = t; i < Nn; i += 256) s1s[i] = s1[b*Nn + i];
    __syncthreads();
    const float s2j = s2[b*Nn + j];
    const float m   = lrelu(s1max[b] + s2j);
    float sum = 0.f;
    const int i0 = part * (Nn/4);
    #pragma unroll 4
    for (int i = i0; i < i0 + Nn/4; ++i)
        sum += __expf(lrelu(s1s[i] + s2j) - m);
    __shared__ float zred[4][64];
    zred[part][jj] = sum;
    __syncthreads();
    if (part == 0)
        invZ[b*Nn + j] = 1.f / (zred[0][jj] + zred[1][jj] + zred[2][jj] + zred[3][jj]);
}

// ---- output store helpers ----
__device__ __forceinline__ void st4(float* p, float4 v){ *(float4*)p = v; }
__device__ __forceinline__ void st4(__hip_bfloat16* p, float4 v){
    ushort4 u; __hip_bfloat16 hv;
    hv = __float2bfloat16(v.x); u.x = *(unsigned short*)&hv;
    hv = __float2bfloat16(v.y); u.y = *(unsigned short*)&hv;
    hv = __float2bfloat16(v.z); u.z = *(unsigned short*)&hv;
    hv = __float2bfloat16(v.w); u.w = *(unsigned short*)&hv;
    *(ushort4*)p = u;
}

// ---- K4: out[b,i,:] = elu( sum_j P[i,j]*Wh[b,j,:] ), flash-style ----
template<typename T, int WANT>
__global__ __launch_bounds__(256) void k_pv(const float* __restrict__ Wh,
                                            const float* __restrict__ s1,
                                            const float* __restrict__ s2,
                                            const float* __restrict__ s1max,
                                            const float* __restrict__ invZ,
                                            const int* __restrict__ flag,
                                            T* __restrict__ out){
    if (flag[0] != WANT) return;
    const int b     = blockIdx.y;
    const int ibase = blockIdx.x * 32;
    const int t     = threadIdx.x;
    const int di = t & 31;   // d-group: d = di*4 .. di*4+3
    const int ii = t >> 5;   // i-group: i = ibase + ii*4 .. +3

    __shared__ float Pt[64][32];   // [j][i]
    __shared__ float s1t[32];
    __shared__ float s2t[64], mt[64], izt[64];
    if (t < 32) s1t[t] = s1[b*Nn + ibase + t];
    const float sm = s1max[b];

    float acc[4][4] = {{0.f,0.f,0.f,0.f},{0.f,0.f,0.f,0.f},{0.f,0.f,0.f,0.f},{0.f,0.f,0.f,0.f}};

    for (int jb = 0; jb < Nn; jb += 64){
        if (t < 64){
            const float v = s2[b*Nn + jb + t];
            s2t[t] = v;
            mt[t]  = lrelu(sm + v);
            izt[t] = invZ[b*Nn + jb + t];
        }
        __syncthreads();
        {   // phase A: fill P tile
            const int ia = t & 31, jg = t >> 5;
            const float s1i = s1t[ia];
            #pragma unroll
            for (int k = 0; k < 8; ++k){
                const int jl = jg*8 + k;
                Pt[jl][ia] = __expf(lrelu(s1i + s2t[jl]) - mt[jl]) * izt[jl];
            }
        }
        __syncthreads();
        // phase B: acc += P^T tile * V tile
        const float* Vb = Wh + (size_t)(b*Nn + jb)*FOUT + di*4;
        #pragma unroll 4
        for (int jl = 0; jl < 64; ++jl){
            const float4 p = *(const float4*)&Pt[jl][ii*4];
            const float4 v = *(const float4*)&Vb[(size_t)jl*FOUT];
            acc[0][0] += p.x*v.x; acc[0][1] += p.x*v.y; acc[0][2] += p.x*v.z; acc[0][3] += p.x*v.w;
            acc[1][0] += p.y*v.x; acc[1][1] += p.y*v.y; acc[1][2] += p.y*v.z; acc[1][3] += p.y*v.w;
            acc[2][0] += p.z*v.x; acc[2][1] += p.z*v.y; acc[2][2] += p.z*v.z; acc[2][3] += p.z*v.w;
            acc[3][0] += p.w*v.x; acc[3][1] += p.w*v.y; acc[3][2] += p.w*v.z; acc[3][3] += p.w*v.w;
        }
        __syncthreads();
    }
    // epilogue: ELU + store
    #pragma unroll
    for (int r = 0; r < 4; ++r){
        const int i = ibase + ii*4 + r;
        float4 o;
        o.x = acc[r][0] > 0.f ? acc[r][0] : expm1f(acc[r][0]);
        o.y = acc[r][1] > 0.f ? acc[r][1] : expm1f(acc[r][1]);
        o.z = acc[r][2] > 0.f ? acc[r][2] : expm1f(acc[r][2]);
        o.w = acc[r][3] > 0.f ? acc[r][3] : expm1f(acc[r][3]);
        st4(&out[((size_t)b*Nn + i)*FOUT + di*4], o);
    }
}

extern "C" void kernel_launch(void* const* d_in, const int* in_sizes, int n_in,
                              void* d_out, int out_size, void* d_ws, size_t ws_size,
                              hipStream_t stream) {
    (void)in_sizes; (void)n_in; (void)out_size; (void)ws_size;

    float* ws    = (float*)d_ws;
    float* Wh    = ws;                       // B*N*FOUT = 2097152 f32
    float* s1    = Wh + (size_t)Bb*Nn*FOUT;  // 16384
    float* s2    = s1 + Bb*Nn;               // 16384
    float* s1max = s2 + Bb*Nn;               // 8 (+pad to 16)
    float* invZ  = s1max + 16;               // 16384
    int*   flag  = (int*)(invZ + Bb*Nn);     // 1

    // dtype probe
    k_flag<<<dim3(1), dim3(64), 0, stream>>>((const unsigned short*)d_in[0], flag);

    // f32 variants (WANT=1)
    k_wh<float,1><<<dim3(Bb*Nn), dim3(128), 0, stream>>>(
        (const float*)d_in[0], (const float*)d_in[1], (const float*)d_in[2],
        flag, Wh, s1, s2);
    // bf16 variants (WANT=0)
    k_wh<__hip_bfloat16,0><<<dim3(Bb*Nn), dim3(128), 0, stream>>>(
        (const __hip_bfloat16*)d_in[0], (const __hip_bfloat16*)d_in[1],
        (const __hip_bfloat16*)d_in[2], flag, Wh, s1, s2);

    k_max<<<dim3(Bb),    dim3(256), 0, stream>>>(s1, s1max);
    k_z  <<<dim3(Bb*32), dim3(256), 0, stream>>>(s1, s2, s1max, invZ);

    k_pv<float,1><<<dim3(Nn/32, Bb), dim3(256), 0, stream>>>(
        Wh, s1, s2, s1max, invZ, flag, (float*)d_out);
    k_pv<__hip_bfloat16,0><<<dim3(Nn/32, Bb), dim3(256), 0, stream>>>(
        Wh, s1, s2, s1max, invZ, flag, (__hip_bfloat16*)d_out);
}

// Round 3
// 145.047 us; speedup vs baseline: 2.4087x; 2.4087x over previous
//
#include <hip/hip_runtime.h>
#include <hip/hip_bf16.h>

// GAT layer: B=8, N=2048, Fin=256, Fout=128  (f32 in / f32 out — proven R2)
// Wh = h@W ; s1 = Wh@a1 ; s2 = Wh@a2
// P[i,j] = exp(lrelu(s1_i+s2_j) - m_j) / Z_j   (softmax over i, per column j)
// out = elu(P @ Wh)
// R3: PV on MFMA bf16; P generated in registers in A-frag layout; V read from
// pre-transposed bf16 WhT so B-frags are contiguous 16B global loads.

#define ALPHA 0.2f
constexpr int Bb=8, Nn=2048, FIN=256, FOUT=128;

typedef __attribute__((ext_vector_type(8))) short short8;
typedef __attribute__((ext_vector_type(4))) float f32x4;

__device__ __forceinline__ float lrelu(float x){ return fmaxf(x, ALPHA*x); }
__device__ __forceinline__ short bfbits(float x){
    __hip_bfloat16 h = __float2bfloat16(x);
    return *(short*)&h;
}

// ---- K1: Wh rows (f32 compute) -> s1, s2 (f32), WhT (bf16, d-major) ----
// 32 rows/block, 256 thr: c=t&15 owns cols c*8..c*8+7, r=t>>4 owns rows r,r+16
__global__ __launch_bounds__(256) void k_wh(const float* __restrict__ h,
                                            const float* __restrict__ W,
                                            const float* __restrict__ a,
                                            float* __restrict__ s1,
                                            float* __restrict__ s2,
                                            __hip_bfloat16* __restrict__ WhT){
    const int blk = blockIdx.x;            // 512 blocks
    const int rowbase = blk * 32;          // global row in [0,16384)
    const int b = blk >> 6;                // 64 blocks per batch
    const int nlocal = rowbase & (Nn-1);
    const int t = threadIdx.x;
    const int c = t & 15, r = t >> 4;

    __shared__ float hs[32*FIN];                    // 32 KB
    __shared__ __hip_bfloat16 tt[FOUT][33];         // transpose buf

    {   // stage h tile (coalesced float4)
        const float4* h4 = (const float4*)(h + (size_t)rowbase*FIN);
        float4* l4 = (float4*)hs;
        #pragma unroll
        for (int v = 0; v < 8; ++v) l4[t + v*256] = h4[t + v*256];
    }
    __syncthreads();

    float acc0[8] = {0,0,0,0,0,0,0,0};
    float acc1[8] = {0,0,0,0,0,0,0,0};
    const float4* W4 = (const float4*)W;
    for (int k = 0; k < FIN; k += 4){
        float ha[4], hb[4];
        *(float4*)ha = *(const float4*)&hs[r*FIN + k];
        *(float4*)hb = *(const float4*)&hs[(r+16)*FIN + k];
        #pragma unroll
        for (int kk = 0; kk < 4; ++kk){
            float wv[8];
            *(float4*)&wv[0] = W4[(k+kk)*32 + c*2];
            *(float4*)&wv[4] = W4[(k+kk)*32 + c*2 + 1];
            #pragma unroll
            for (int e = 0; e < 8; ++e){
                acc0[e] += ha[kk] * wv[e];
                acc1[e] += hb[kk] * wv[e];
            }
        }
    }

    // s1/s2: partial over this thread's 8 cols, reduce across 16 c-lanes
    {
        const float4* a4 = (const float4*)a;
        float a1v[8], a2v[8];
        *(float4*)&a1v[0] = a4[c*2];      *(float4*)&a1v[4] = a4[c*2+1];
        *(float4*)&a2v[0] = a4[32+c*2];   *(float4*)&a2v[4] = a4[32+c*2+1];
        float p10=0, p20=0, p11=0, p21=0;
        #pragma unroll
        for (int e = 0; e < 8; ++e){
            p10 += acc0[e]*a1v[e]; p20 += acc0[e]*a2v[e];
            p11 += acc1[e]*a1v[e]; p21 += acc1[e]*a2v[e];
        }
        #pragma unroll
        for (int m = 1; m < 16; m <<= 1){
            p10 += __shfl_xor(p10, m); p20 += __shfl_xor(p20, m);
            p11 += __shfl_xor(p11, m); p21 += __shfl_xor(p21, m);
        }
        if (c == 0){
            s1[rowbase + r]      = p10;  s2[rowbase + r]      = p20;
            s1[rowbase + r + 16] = p11;  s2[rowbase + r + 16] = p21;
        }
    }

    // WhT: via LDS transpose, bf16
    #pragma unroll
    for (int e = 0; e < 8; ++e){
        tt[c*8+e][r]      = __float2bfloat16(acc0[e]);
        tt[c*8+e][r+16]   = __float2bfloat16(acc1[e]);
    }
    __syncthreads();
    {
        const int d = t >> 1, jh = (t & 1) * 16;
        short8 v0, v1;
        #pragma unroll
        for (int x = 0; x < 8; ++x){
            __hip_bfloat16 b0 = tt[d][jh + x], b1 = tt[d][jh + 8 + x];
            v0[x] = *(short*)&b0; v1[x] = *(short*)&b1;
        }
        short* Wt = (short*)WhT;
        size_t base = ((size_t)(b*FOUT + d))*Nn + nlocal + jh;
        *(short8*)&Wt[base]     = v0;
        *(short8*)&Wt[base + 8] = v1;
    }
}

// ---- K2: s1max[b] = max_i s1[b,i] ----
__global__ __launch_bounds__(256) void k_max(const float* __restrict__ s1,
                                             float* __restrict__ s1max){
    const int b = blockIdx.x, t = threadIdx.x;
    float m = -1e30f;
    for (int i = t; i < Nn; i += 256) m = fmaxf(m, s1[b*Nn + i]);
    #pragma unroll
    for (int off = 32; off > 0; off >>= 1) m = fmaxf(m, __shfl_down(m, off));
    __shared__ float red[4];
    if ((t & 63) == 0) red[t >> 6] = m;
    __syncthreads();
    if (t == 0) s1max[b] = fmaxf(fmaxf(red[0], red[1]), fmaxf(red[2], red[3]));
}

// ---- K3: zz[b,j] = exp(-m_j) / Z_j ----
// 1024 blocks: 16 j's x 16 partials of 128 i's each
__global__ __launch_bounds__(256) void k_z(const float* __restrict__ s1,
                                           const float* __restrict__ s2,
                                           const float* __restrict__ s1max,
                                           float* __restrict__ zz){
    const int b  = blockIdx.x >> 7;
    const int jt = blockIdx.x & 127;
    const int t  = threadIdx.x;
    const int jj = t & 15, part = t >> 4;
    const int j  = jt*16 + jj;
    __shared__ float s1s[Nn];
    for (int i = t; i < Nn; i += 256) s1s[i] = s1[b*Nn + i];
    __syncthreads();
    const float s2j = s2[b*Nn + j];
    const float m   = lrelu(s1max[b] + s2j);
    float sum = 0.f;
    const float4* s4 = (const float4*)&s1s[part*128];
    #pragma unroll 4
    for (int v = 0; v < 32; ++v){
        float x[4]; *(float4*)x = s4[v];
        sum += __expf(lrelu(x[0]+s2j) - m) + __expf(lrelu(x[1]+s2j) - m)
             + __expf(lrelu(x[2]+s2j) - m) + __expf(lrelu(x[3]+s2j) - m);
    }
    __shared__ float red[16][17];
    red[part][jj] = sum;
    __syncthreads();
    if (part == 0){
        float Z = 0.f;
        #pragma unroll
        for (int p = 0; p < 16; ++p) Z += red[p][jj];
        zz[b*Nn + j] = __expf(-m) / Z;
    }
}

// ---- K4: out = elu(P @ Wh) via MFMA 16x16x32 bf16 ----
// Block: 64 i x 128 d, 4 waves (wm = m-tile of 32, wn = n-half of 64).
// A = P built in registers (m=lane&15, k=(lane>>4)*8+e), B from WhT (16B loads).
__global__ __launch_bounds__(256) void k_pv(const float* __restrict__ s1,
                                            const float* __restrict__ s2,
                                            const float* __restrict__ zz,
                                            const __hip_bfloat16* __restrict__ WhT,
                                            float* __restrict__ out){
    const int b     = blockIdx.y;
    const int ibase = blockIdx.x * 64;
    const int t     = threadIdx.x;
    const int wave  = t >> 6, lane = t & 63;
    const int wm = wave & 1, wn = wave >> 1;
    const int lm = lane & 15, q = lane >> 4;

    __shared__ float s2s[Nn], zzs[Nn];   // 16 KB
    {
        const float4* g1 = (const float4*)(s2 + (size_t)b*Nn);
        const float4* g2 = (const float4*)(zz + (size_t)b*Nn);
        float4* l1 = (float4*)s2s; float4* l2 = (float4*)zzs;
        for (int v = t; v < Nn/4; v += 256){ l1[v] = g1[v]; l2[v] = g2[v]; }
    }
    __syncthreads();

    const int i0 = ibase + wm*32 + lm;
    const float s1a = s1[(size_t)b*Nn + i0];
    const float s1b = s1[(size_t)b*Nn + i0 + 16];

    f32x4 acc[2][4];
    #pragma unroll
    for (int mt = 0; mt < 2; ++mt)
        #pragma unroll
        for (int nt = 0; nt < 4; ++nt) acc[mt][nt] = (f32x4){0.f,0.f,0.f,0.f};

    const short* Wt = (const short*)WhT;
    const short* Brow[4];
    #pragma unroll
    for (int nt = 0; nt < 4; ++nt)
        Brow[nt] = Wt + ((size_t)(b*FOUT + wn*64 + nt*16 + lm))*Nn + q*8;

    for (int jb = 0; jb < Nn; jb += 32){
        const int jl = jb + q*8;
        float s2a[8], zza[8];
        *(float4*)&s2a[0] = *(const float4*)&s2s[jl];
        *(float4*)&s2a[4] = *(const float4*)&s2s[jl+4];
        *(float4*)&zza[0] = *(const float4*)&zzs[jl];
        *(float4*)&zza[4] = *(const float4*)&zzs[jl+4];

        short8 bfr[4];
        #pragma unroll
        for (int nt = 0; nt < 4; ++nt)
            bfr[nt] = *(const short8*)(Brow[nt] + jb);

        short8 afa, afb;
        #pragma unroll
        for (int e = 0; e < 8; ++e){
            const float t0 = s1a + s2a[e];
            const float t1 = s1b + s2a[e];
            afa[e] = bfbits(__expf(lrelu(t0)) * zza[e]);
            afb[e] = bfbits(__expf(lrelu(t1)) * zza[e]);
        }

        #pragma unroll
        for (int nt = 0; nt < 4; ++nt){
            acc[0][nt] = __builtin_amdgcn_mfma_f32_16x16x32_bf16(afa, bfr[nt], acc[0][nt], 0,0,0);
            acc[1][nt] = __builtin_amdgcn_mfma_f32_16x16x32_bf16(afb, bfr[nt], acc[1][nt], 0,0,0);
        }
    }

    // epilogue: ELU + f32 store. C/D: col=lane&15, row=(lane>>4)*4+reg
    #pragma unroll
    for (int mt = 0; mt < 2; ++mt){
        #pragma unroll
        for (int nt = 0; nt < 4; ++nt){
            const int col = wn*64 + nt*16 + lm;
            #pragma unroll
            for (int rg = 0; rg < 4; ++rg){
                const int row = ibase + wm*32 + mt*16 + q*4 + rg;
                const float x = acc[mt][nt][rg];
                out[((size_t)(b*Nn + row))*FOUT + col] = x > 0.f ? x : expm1f(x);
            }
        }
    }
}

extern "C" void kernel_launch(void* const* d_in, const int* in_sizes, int n_in,
                              void* d_out, int out_size, void* d_ws, size_t ws_size,
                              hipStream_t stream) {
    (void)in_sizes; (void)n_in; (void)out_size; (void)ws_size;
    const float* h = (const float*)d_in[0];
    const float* W = (const float*)d_in[1];
    const float* a = (const float*)d_in[2];
    float* out = (float*)d_out;

    float* ws    = (float*)d_ws;
    float* s1    = ws;                    // 16384
    float* s2    = s1 + Bb*Nn;            // 16384
    float* zz    = s2 + Bb*Nn;            // 16384
    float* s1max = zz + Bb*Nn;            // 16 (pad)
    __hip_bfloat16* WhT = (__hip_bfloat16*)(s1max + 16);  // 8*128*2048 bf16 = 4 MB

    k_wh <<<dim3(Bb*Nn/32), dim3(256), 0, stream>>>(h, W, a, s1, s2, WhT);
    k_max<<<dim3(Bb),       dim3(256), 0, stream>>>(s1, s1max);
    k_z  <<<dim3(Bb*128),   dim3(256), 0, stream>>>(s1, s2, s1max, zz);
    k_pv <<<dim3(Nn/64, Bb), dim3(256), 0, stream>>>(s1, s2, zz, WhT, out);
}